// Round 1
// baseline (2864.396 us; speedup 1.0000x reference)
//
#include <hip/hip_runtime.h>
#include <hip/hip_bf16.h>
#include <math.h>

#define N_ATOMS 50000
#define N_EDGES 1600000
#define FDIM 128
#define NB 25
#define CUTOFF_F 5.0f
#define PI_OVER_CUTOFF 0.6283185307179586f

__device__ __forceinline__ float swish_f(float v) {
    return v / (1.0f + __expf(-v));
}

// out[r][c] = act(sum_k A[r][k]*W[k][c] + bias[c]); A:[n_rows,128], W:[128,128]
__global__ __launch_bounds__(256, 4) void node_gemm_kernel(
    const float* __restrict__ A, const float* __restrict__ W,
    const float* __restrict__ bias, float* __restrict__ out,
    int n_rows, int do_swish)
{
    __shared__ float As[32 * 132];   // 32 rows x 128 cols, padded stride 132
    __shared__ float Ws[16 * 128];   // K-chunk of W

    const int t = threadIdx.x;
    const int row0 = blockIdx.x * 32;
    const int c4 = (t & 31) * 4;     // output column base
    const int rb = (t >> 5) * 4;     // output row base within tile

    // stage A tile (zero-fill out-of-range rows)
    for (int v = t; v < 1024; v += 256) {
        int r = v >> 5;
        int c = (v & 31) * 4;
        float4 val;
        if (row0 + r < n_rows) val = *(const float4*)&A[(size_t)(row0 + r) * FDIM + c];
        else val = make_float4(0.f, 0.f, 0.f, 0.f);
        *(float4*)&As[r * 132 + c] = val;
    }

    float acc[4][4];
    #pragma unroll
    for (int i = 0; i < 4; ++i)
        #pragma unroll
        for (int j = 0; j < 4; ++j) acc[i][j] = 0.f;

    for (int k0 = 0; k0 < 128; k0 += 16) {
        __syncthreads();  // covers As staging (first iter) + prior Ws reads
        for (int v = t; v < 512; v += 256)
            *(float4*)&Ws[v * 4] = *(const float4*)&W[k0 * 128 + v * 4];
        __syncthreads();
        #pragma unroll
        for (int kq = 0; kq < 4; ++kq) {
            const int kk = kq * 4;
            float4 w0 = *(float4*)&Ws[(kk + 0) * 128 + c4];
            float4 w1 = *(float4*)&Ws[(kk + 1) * 128 + c4];
            float4 w2 = *(float4*)&Ws[(kk + 2) * 128 + c4];
            float4 w3 = *(float4*)&Ws[(kk + 3) * 128 + c4];
            #pragma unroll
            for (int i = 0; i < 4; ++i) {
                float4 av = *(float4*)&As[(rb + i) * 132 + k0 + kk];
                acc[i][0] += av.x * w0.x + av.y * w1.x + av.z * w2.x + av.w * w3.x;
                acc[i][1] += av.x * w0.y + av.y * w1.y + av.z * w2.y + av.w * w3.y;
                acc[i][2] += av.x * w0.z + av.y * w1.z + av.z * w2.z + av.w * w3.z;
                acc[i][3] += av.x * w0.w + av.y * w1.w + av.z * w2.w + av.w * w3.w;
            }
        }
    }

    float4 bv = make_float4(0.f, 0.f, 0.f, 0.f);
    if (bias) bv = *(const float4*)&bias[c4];
    #pragma unroll
    for (int i = 0; i < 4; ++i) {
        int r = row0 + rb + i;
        if (r < n_rows) {
            float4 o;
            o.x = acc[i][0] + bv.x;
            o.y = acc[i][1] + bv.y;
            o.z = acc[i][2] + bv.z;
            o.w = acc[i][3] + bv.w;
            if (do_swish) {
                o.x = swish_f(o.x); o.y = swish_f(o.y);
                o.z = swish_f(o.z); o.w = swish_f(o.w);
            }
            *(float4*)&out[(size_t)r * FDIM + c4] = o;
        }
    }
}

// Fused edge kernel: per 64-edge tile
//   H = swish(fij @ W_f1 + b_f1)            [64 x 128]
//   Wfilt = H @ W_f2 + b_f2                 [64 x 128] (in registers)
//   m = x[src] * Wfilt * C(rij); atomicAdd into agg[dst]
__global__ __launch_bounds__(256, 2) void edge_kernel(
    const float* __restrict__ fij, const float* __restrict__ rij,
    const int* __restrict__ src, const int* __restrict__ dst,
    const float* __restrict__ W1, const float* __restrict__ b1,
    const float* __restrict__ W2, const float* __restrict__ b2,
    const float* __restrict__ x, float* __restrict__ agg)
{
    __shared__ float fsT[NB * 72];    // fij tile transposed: [k][e], stride 72
    __shared__ float Hs[64 * 132];    // H tile: [e][c], stride 132
    __shared__ float W2s[16 * 128];   // K-chunk of W2

    const int t = threadIdx.x;
    const int e0 = blockIdx.x * 64;
    const int c4 = (t & 31) * 4;      // column base (0..124)
    const int eb = (t >> 5) * 8;      // edge base within tile (0..56)

    // Phase 0: stage fij tile transposed into LDS
    {
        const int base = e0 * NB;
        for (int idx = t; idx < 64 * NB; idx += 256) {
            float v = fij[base + idx];
            int e = idx / NB;
            int k = idx - e * NB;
            fsT[k * 72 + e] = v;
        }
    }
    __syncthreads();

    // Phase 1: H tile -> Hs
    {
        float h[8][4];
        #pragma unroll
        for (int i = 0; i < 8; ++i)
            #pragma unroll
            for (int j = 0; j < 4; ++j) h[i][j] = 0.f;

        for (int k = 0; k < NB; ++k) {
            float4 w = *(const float4*)&W1[k * 128 + c4];  // L1-resident (12.8KB)
            float4 fa = *(float4*)&fsT[k * 72 + eb];
            float4 fb = *(float4*)&fsT[k * 72 + eb + 4];
            float fe[8] = {fa.x, fa.y, fa.z, fa.w, fb.x, fb.y, fb.z, fb.w};
            #pragma unroll
            for (int i = 0; i < 8; ++i) {
                h[i][0] += fe[i] * w.x;
                h[i][1] += fe[i] * w.y;
                h[i][2] += fe[i] * w.z;
                h[i][3] += fe[i] * w.w;
            }
        }
        float4 b1v = *(const float4*)&b1[c4];
        #pragma unroll
        for (int i = 0; i < 8; ++i) {
            float4 o;
            o.x = swish_f(h[i][0] + b1v.x);
            o.y = swish_f(h[i][1] + b1v.y);
            o.z = swish_f(h[i][2] + b1v.z);
            o.w = swish_f(h[i][3] + b1v.w);
            *(float4*)&Hs[(eb + i) * 132 + c4] = o;
        }
    }

    // Phase 2: Wfilt tile = Hs @ W2 (register accumulation)
    float acc[8][4];
    #pragma unroll
    for (int i = 0; i < 8; ++i)
        #pragma unroll
        for (int j = 0; j < 4; ++j) acc[i][j] = 0.f;

    for (int k0 = 0; k0 < 128; k0 += 16) {
        __syncthreads();  // covers Hs writes (first iter) + prior W2s reads
        for (int v = t; v < 512; v += 256)
            *(float4*)&W2s[v * 4] = *(const float4*)&W2[k0 * 128 + v * 4];
        __syncthreads();
        #pragma unroll
        for (int kq = 0; kq < 4; ++kq) {
            const int kk = kq * 4;
            float4 w0 = *(float4*)&W2s[(kk + 0) * 128 + c4];
            float4 w1 = *(float4*)&W2s[(kk + 1) * 128 + c4];
            float4 w2 = *(float4*)&W2s[(kk + 2) * 128 + c4];
            float4 w3 = *(float4*)&W2s[(kk + 3) * 128 + c4];
            #pragma unroll
            for (int i = 0; i < 8; ++i) {
                float4 hv = *(float4*)&Hs[(eb + i) * 132 + k0 + kk];
                acc[i][0] += hv.x * w0.x + hv.y * w1.x + hv.z * w2.x + hv.w * w3.x;
                acc[i][1] += hv.x * w0.y + hv.y * w1.y + hv.z * w2.y + hv.w * w3.y;
                acc[i][2] += hv.x * w0.z + hv.y * w1.z + hv.z * w2.z + hv.w * w3.z;
                acc[i][3] += hv.x * w0.w + hv.y * w1.w + hv.z * w2.w + hv.w * w3.w;
            }
        }
    }

    // Epilogue: cutoff, gather x[src], scatter-add to agg[dst]
    {
        float4 b2v = *(const float4*)&b2[c4];
        #pragma unroll
        for (int i = 0; i < 8; ++i) {
            int e = e0 + eb + i;
            float r = rij[e];
            float Cf = (r < CUTOFF_F) ? 0.5f * (__cosf(r * PI_OVER_CUTOFF) + 1.0f) : 0.0f;
            int s = src[e];
            int d = dst[e];
            float4 xv = *(const float4*)&x[(size_t)s * FDIM + c4];
            float m0 = xv.x * (acc[i][0] + b2v.x) * Cf;
            float m1 = xv.y * (acc[i][1] + b2v.y) * Cf;
            float m2 = xv.z * (acc[i][2] + b2v.z) * Cf;
            float m3 = xv.w * (acc[i][3] + b2v.w) * Cf;
            float* ap = &agg[(size_t)d * FDIM + c4];
            unsafeAtomicAdd(ap + 0, m0);
            unsafeAtomicAdd(ap + 1, m1);
            unsafeAtomicAdd(ap + 2, m2);
            unsafeAtomicAdd(ap + 3, m3);
        }
    }
}

extern "C" void kernel_launch(void* const* d_in, const int* in_sizes, int n_in,
                              void* d_out, int out_size, void* d_ws, size_t ws_size,
                              hipStream_t stream)
{
    const float* feat   = (const float*)d_in[0];
    const float* fij    = (const float*)d_in[1];
    const float* rij    = (const float*)d_in[2];
    const int*   src    = (const int*)d_in[3];
    const int*   dst    = (const int*)d_in[4];
    const float* W_in2f = (const float*)d_in[5];
    const float* W_f1   = (const float*)d_in[6];
    const float* b_f1   = (const float*)d_in[7];
    const float* W_f2   = (const float*)d_in[8];
    const float* b_f2   = (const float*)d_in[9];
    const float* W_out  = (const float*)d_in[10];
    const float* b_out  = (const float*)d_in[11];
    float* out = (float*)d_out;

    float* x   = (float*)d_ws;                       // [N_ATOMS,128] = 25.6 MB
    float* agg = x + (size_t)N_ATOMS * FDIM;         // [N_ATOMS,128] = 25.6 MB

    hipMemsetAsync(agg, 0, (size_t)N_ATOMS * FDIM * sizeof(float), stream);

    node_gemm_kernel<<<(N_ATOMS + 31) / 32, 256, 0, stream>>>(
        feat, W_in2f, nullptr, x, N_ATOMS, 0);

    edge_kernel<<<N_EDGES / 64, 256, 0, stream>>>(
        fij, rij, src, dst, W_f1, b_f1, W_f2, b_f2, x, agg);

    node_gemm_kernel<<<(N_ATOMS + 31) / 32, 256, 0, stream>>>(
        agg, W_out, b_out, out, N_ATOMS, 1);
}

// Round 2
// 792.354 us; speedup vs baseline: 3.6150x; 3.6150x over previous
//
#include <hip/hip_runtime.h>
#include <hip/hip_bf16.h>
#include <math.h>

#define N_ATOMS 50000
#define N_EDGES 1600000
#define FDIM 128
#define NB 25
#define CUTOFF_F 5.0f
#define PI_OVER_CUTOFF 0.6283185307179586f

typedef __bf16 bf16x8 __attribute__((ext_vector_type(8)));
typedef float f32x4 __attribute__((ext_vector_type(4)));

__device__ __forceinline__ float swish_f(float v) {
    return v / (1.0f + __expf(-v));
}

// XOR swizzle on 16B slots; distinguishes rows 8 apart via bit3.
#define SWZ(row) ((((row) & 7) ^ (((row) >> 3) & 1)) << 4)

// Pack W [K_eff x 128] f32 into MFMA B-fragments (bf16), K zero-padded to KS*32.
// Fragment (ks, n): lane l, elem j holds W[ks*32 + (l>>4)*8 + j][n*16 + (l&15)].
__global__ void pack_b_kernel(const float* __restrict__ W, __bf16* __restrict__ out,
                              int K_eff, int KS)
{
    int idx = blockIdx.x * 256 + threadIdx.x;
    int total = KS * 8 * 64 * 8;
    if (idx >= total) return;
    int j  = idx & 7;
    int l  = (idx >> 3) & 63;
    int n  = (idx >> 9) & 7;
    int ks = idx >> 12;
    int k   = ks * 32 + ((l >> 4) << 3) + j;
    int col = (n << 4) + (l & 15);
    float v = (k < K_eff) ? W[k * FDIM + col] : 0.0f;
    out[idx] = (__bf16)v;
}

// out[r][c] = act(sum_k A[r][k]*W[k][c] + bias[c]); A:[n_rows,128], W:[128,128]
__global__ __launch_bounds__(256, 4) void node_gemm_kernel(
    const float* __restrict__ A, const float* __restrict__ W,
    const float* __restrict__ bias, float* __restrict__ out,
    int n_rows, int do_swish)
{
    __shared__ float As[32 * 132];
    __shared__ float Ws[16 * 128];

    const int t = threadIdx.x;
    const int row0 = blockIdx.x * 32;
    const int c4 = (t & 31) * 4;
    const int rb = (t >> 5) * 4;

    for (int v = t; v < 1024; v += 256) {
        int r = v >> 5;
        int c = (v & 31) * 4;
        float4 val;
        if (row0 + r < n_rows) val = *(const float4*)&A[(size_t)(row0 + r) * FDIM + c];
        else val = make_float4(0.f, 0.f, 0.f, 0.f);
        *(float4*)&As[r * 132 + c] = val;
    }

    float acc[4][4];
    #pragma unroll
    for (int i = 0; i < 4; ++i)
        #pragma unroll
        for (int j = 0; j < 4; ++j) acc[i][j] = 0.f;

    for (int k0 = 0; k0 < 128; k0 += 16) {
        __syncthreads();
        for (int v = t; v < 512; v += 256)
            *(float4*)&Ws[v * 4] = *(const float4*)&W[k0 * 128 + v * 4];
        __syncthreads();
        #pragma unroll
        for (int kq = 0; kq < 4; ++kq) {
            const int kk = kq * 4;
            float4 w0 = *(float4*)&Ws[(kk + 0) * 128 + c4];
            float4 w1 = *(float4*)&Ws[(kk + 1) * 128 + c4];
            float4 w2 = *(float4*)&Ws[(kk + 2) * 128 + c4];
            float4 w3 = *(float4*)&Ws[(kk + 3) * 128 + c4];
            #pragma unroll
            for (int i = 0; i < 4; ++i) {
                float4 av = *(float4*)&As[(rb + i) * 132 + k0 + kk];
                acc[i][0] += av.x * w0.x + av.y * w1.x + av.z * w2.x + av.w * w3.x;
                acc[i][1] += av.x * w0.y + av.y * w1.y + av.z * w2.y + av.w * w3.y;
                acc[i][2] += av.x * w0.z + av.y * w1.z + av.z * w2.z + av.w * w3.z;
                acc[i][3] += av.x * w0.w + av.y * w1.w + av.z * w2.w + av.w * w3.w;
            }
        }
    }

    float4 bv = make_float4(0.f, 0.f, 0.f, 0.f);
    if (bias) bv = *(const float4*)&bias[c4];
    #pragma unroll
    for (int i = 0; i < 4; ++i) {
        int r = row0 + rb + i;
        if (r < n_rows) {
            float4 o;
            o.x = acc[i][0] + bv.x;
            o.y = acc[i][1] + bv.y;
            o.z = acc[i][2] + bv.z;
            o.w = acc[i][3] + bv.w;
            if (do_swish) {
                o.x = swish_f(o.x); o.y = swish_f(o.y);
                o.z = swish_f(o.z); o.w = swish_f(o.w);
            }
            *(float4*)&out[(size_t)r * FDIM + c4] = o;
        }
    }
}

// MFMA edge kernel: 64 edges/block, 4 waves, each wave owns a 16-edge strip.
//   H[64x128]   = swish(fij_pad[64x32] @ W1p + b1)      (1 MFMA k-step)
//   Wfilt[64x128] = H @ W2p + b2                        (4 MFMA k-steps)
//   m = x[src] * Wfilt * C(rij) -> atomicAdd agg[dst]
__global__ __launch_bounds__(256, 4) void edge_kernel(
    const float* __restrict__ fij, const float* __restrict__ rij,
    const int* __restrict__ src, const int* __restrict__ dst,
    const __bf16* __restrict__ w1p, const float* __restrict__ b1,
    const __bf16* __restrict__ w2p, const float* __restrict__ b2,
    const float* __restrict__ x, float* __restrict__ agg)
{
    __shared__ float fs[64 * 32];     // fij tile, f32, zero-padded K, swizzled
    __shared__ __bf16 hs[64 * 128];   // H tile, bf16, swizzled

    const int t = threadIdx.x;
    const int l = t & 63;
    const int w = t >> 6;
    const int e0 = blockIdx.x * 64;
    const int lrow = l & 15;
    const int kgrp = l >> 4;
    const int row = (w << 4) | lrow;  // A-fragment row (edge within tile)

    // Stage fij tile -> fs (coalesced global read, swizzled LDS write)
    for (int idx = t; idx < 64 * 32; idx += 256) {
        int e = idx >> 5;
        int k = idx & 31;
        float v = (k < NB) ? fij[(size_t)(e0 + e) * NB + k] : 0.0f;
        int byte = (e << 7) + (k << 2);
        byte ^= SWZ(e);
        *(float*)((char*)fs + byte) = v;
    }
    __syncthreads();

    const f32x4 zero = {0.f, 0.f, 0.f, 0.f};

    // GEMM1: H strip for this wave; write swish(H) to hs as bf16
    {
        int b0 = (row << 7) + (kgrp << 5);
        b0 ^= SWZ(row);
        float4 flo = *(const float4*)((const char*)fs + b0);
        float4 fhi = *(const float4*)((const char*)fs + (b0 ^ 16));
        bf16x8 a;
        a[0] = (__bf16)flo.x; a[1] = (__bf16)flo.y; a[2] = (__bf16)flo.z; a[3] = (__bf16)flo.w;
        a[4] = (__bf16)fhi.x; a[5] = (__bf16)fhi.y; a[6] = (__bf16)fhi.z; a[7] = (__bf16)fhi.w;

        #pragma unroll
        for (int n = 0; n < 8; ++n) {
            bf16x8 b = *(const bf16x8*)(w1p + (((n << 6) + l) << 3));
            f32x4 h = __builtin_amdgcn_mfma_f32_16x16x32_bf16(a, b, zero, 0, 0, 0);
            float bb = b1[(n << 4) + lrow];
            #pragma unroll
            for (int r = 0; r < 4; ++r) {
                int hrow = (w << 4) + (kgrp << 2) + r;   // C-layout row
                float hv = swish_f(h[r] + bb);
                int byte = (hrow << 8) + (((n << 4) + lrow) << 1);
                byte ^= SWZ(hrow);
                *(__bf16*)((char*)hs + byte) = (__bf16)hv;
            }
        }
    }
    __syncthreads();

    // GEMM2: Wfilt strip = H @ W2 (B-frags streamed from L2)
    f32x4 acc[8];
    #pragma unroll
    for (int n = 0; n < 8; ++n) acc[n] = zero;

    #pragma unroll
    for (int ks = 0; ks < 4; ++ks) {
        int byte = (row << 8) + (ks << 6) + (kgrp << 4);
        byte ^= SWZ(row);
        bf16x8 a = *(const bf16x8*)((const char*)hs + byte);
        #pragma unroll
        for (int n = 0; n < 8; ++n) {
            bf16x8 b = *(const bf16x8*)(w2p + ((((ks << 3) + n) << 6) + l) * 8);
            acc[n] = __builtin_amdgcn_mfma_f32_16x16x32_bf16(a, b, acc[n], 0, 0, 0);
        }
    }

    // Epilogue: cutoff, gather x[src], scatter-add agg[dst]
    {
        const int els = (w << 4) + (kgrp << 2);   // first of this lane's 4 edges
        float Cf[4]; int se[4]; int de[4];
        #pragma unroll
        for (int r = 0; r < 4; ++r) {
            int e = e0 + els + r;
            float rr = rij[e];
            Cf[r] = (rr < CUTOFF_F) ? 0.5f * (__cosf(rr * PI_OVER_CUTOFF) + 1.0f) : 0.0f;
            se[r] = src[e];
            de[r] = dst[e];
        }
        #pragma unroll
        for (int n = 0; n < 8; ++n) {
            int col = (n << 4) + lrow;
            float b2v = b2[col];
            #pragma unroll
            for (int r = 0; r < 4; ++r) {
                float wf = acc[n][r] + b2v;
                float m = x[(size_t)se[r] * FDIM + col] * wf * Cf[r];
                unsafeAtomicAdd(&agg[(size_t)de[r] * FDIM + col], m);
            }
        }
    }
}

extern "C" void kernel_launch(void* const* d_in, const int* in_sizes, int n_in,
                              void* d_out, int out_size, void* d_ws, size_t ws_size,
                              hipStream_t stream)
{
    const float* feat   = (const float*)d_in[0];
    const float* fij    = (const float*)d_in[1];
    const float* rij    = (const float*)d_in[2];
    const int*   src    = (const int*)d_in[3];
    const int*   dst    = (const int*)d_in[4];
    const float* W_in2f = (const float*)d_in[5];
    const float* W_f1   = (const float*)d_in[6];
    const float* b_f1   = (const float*)d_in[7];
    const float* W_f2   = (const float*)d_in[8];
    const float* b_f2   = (const float*)d_in[9];
    const float* W_out  = (const float*)d_in[10];
    const float* b_out  = (const float*)d_in[11];
    float* out = (float*)d_out;

    float*  x   = (float*)d_ws;                          // [N_ATOMS,128] f32
    __bf16* w1p = (__bf16*)(x + (size_t)N_ATOMS * FDIM); // 4096 bf16
    __bf16* w2p = w1p + 4096;                            // 16384 bf16
    float*  agg = out;                                   // accumulate into d_out

    hipMemsetAsync(agg, 0, (size_t)N_ATOMS * FDIM * sizeof(float), stream);

    pack_b_kernel<<<(4096 + 255) / 256, 256, 0, stream>>>(W_f1, w1p, NB, 1);
    pack_b_kernel<<<(16384 + 255) / 256, 256, 0, stream>>>(W_f2, w2p, 128, 4);

    node_gemm_kernel<<<(N_ATOMS + 31) / 32, 256, 0, stream>>>(
        feat, W_in2f, nullptr, x, N_ATOMS, 0);

    edge_kernel<<<N_EDGES / 64, 256, 0, stream>>>(
        fij, rij, src, dst, w1p, b_f1, w2p, b_f2, x, agg);

    // in-place: each block reads only the rows it writes
    node_gemm_kernel<<<(N_ATOMS + 31) / 32, 256, 0, stream>>>(
        agg, W_out, b_out, out, N_ATOMS, 1);
}